// Round 2
// baseline (1283.968 us; speedup 1.0000x reference)
//
#include <hip/hip_runtime.h>

typedef __attribute__((ext_vector_type(8))) short short8;
typedef __attribute__((ext_vector_type(4))) float f32x4;

#define MFMA16(a, b, c) __builtin_amdgcn_mfma_f32_16x16x32_bf16((a), (b), (c), 0, 0, 0)

constexpr int Bv  = 32;    // batch
constexpr int Lv  = 168;   // encoder length
constexpr int Sv  = 512;   // sites
constexpr int HZv = 24;    // horizon
constexpr int Mv  = 16;    // sequences per block (1024 blocks, 4 per CU)
constexpr int HSTR = 88;   // h-row stride (shorts)
constexpr int HBUF = Mv * HSTR;   // 1408 shorts per buffer
// LDS pad: push static LDS to ~39.4 KB so EXACTLY 4 blocks fit per CU
// (4 x 39.4 KB < 160 KB < 5 x 39.4 KB). 1024 blocks / 256 CUs = 4 each ->
// 16 waves/CU = 4 independent instruction streams per SIMD (r15 had 2;
// VALU port was 30% idle from uncovered per-wave issue gaps).
constexpr int PADv = 13900;

__device__ __forceinline__ float b2f(short s) {
    unsigned u = ((unsigned)(unsigned short)s) << 16;
    return __builtin_bit_cast(float, u);
}
__device__ __forceinline__ short f2b(float f) {
    unsigned u = __builtin_bit_cast(unsigned, f);
    unsigned r = (u + 0x7FFFu + ((u >> 16) & 1u)) >> 16;   // RNE
    return (short)(unsigned short)r;
}
// no clamps: exp2(inf)=inf, rcp(inf)=0 give exact saturation, no NaN path
__device__ __forceinline__ float sigm(float x) {
    float e = __builtin_amdgcn_exp2f(-1.44269504088896f * x);
    return __builtin_amdgcn_rcpf(1.0f + e);
}
__device__ __forceinline__ float tanh_(float x) {
    float e = __builtin_amdgcn_exp2f(2.88539008177793f * x); // exp(2x)
    return 1.0f - 2.0f * __builtin_amdgcn_rcpf(e + 1.0f);
}
__device__ __forceinline__ void hi8(const float* __restrict__ p, short8& hi) {
#pragma unroll
    for (int j = 0; j < 8; ++j) hi[j] = f2b(p[j]);
}

// r16: M=16 / 256-thread blocks / grid=1024 -> 4 blocks/CU = 16 waves/CU,
// 4 independent streams per SIMD. Math byte-identical to r15. Hazard
// structure identical (ONE barrier per encoder step; all cross-step RAW/WAR
// pairs separated by exactly one barrier).
__global__ __launch_bounds__(256, 4)
void sitewise_lstm(const float* __restrict__ x_seq,
                   const float* __restrict__ Wih0, const float* __restrict__ Whh0,
                   const float* __restrict__ bih0, const float* __restrict__ bhh0,
                   const float* __restrict__ Wih1, const float* __restrict__ Whh1,
                   const float* __restrict__ bih1, const float* __restrict__ bhh1,
                   const float* __restrict__ Wcih, const float* __restrict__ Wchh,
                   const float* __restrict__ bcih, const float* __restrict__ bchh,
                   const float* __restrict__ Wout, const float* __restrict__ bout,
                   float* __restrict__ out)
{
    __shared__ __align__(16) short Hhi[4 * HBUF + PADv];   // ~39.1 KB
    __shared__ float woutF[64];
    __shared__ float ybufF[Mv];

    const int tid  = threadIdx.x;
    const int wv   = tid >> 6;    // wave = U-slice, 0..3
    const int lane = tid & 63;
    const int q    = lane >> 4;
    const int col  = lane & 15;
    const int U    = wv;          // unit-slice: u in [16U, 16U+16)
    const int bid  = blockIdx.x;
    const int b    = bid >> 5;
    const int s0   = (bid & 31) << 4;
    const int uu   = U * 16 + col;
    const int me   = q * 4;                   // epilogue m base (+ r)

    for (int i = tid; i < 4 * HBUF / 2; i += 256) ((int*)Hhi)[i] = 0;
    if (tid < 64) woutF[tid] = Wout[tid];

    const float* xbF = x_seq + b * Lv * Sv + s0;

    const int roA = col * HSTR + q * 8;       // + kc*32
    const int wiA = me * HSTR + uu;           // + r*HSTR

    // ---- per-wave weights: 4 gate-tiles x 2 kc per matrix, single bf16 (RNE) ----
    short8 Whi[3][4][2];   // [Whh0|Wih1|Whh1][g][kc]; slot0 -> Wchh in decoder
    float bias0[4], bias1[4], biasc[4], wih0gE[4], wcihgE[4];
#pragma unroll
    for (int g = 0; g < 4; ++g) {
        const int j = g * 64 + uu;
        bias0[g] = bih0[j] + bhh0[j];
        bias1[g] = bih1[j] + bhh1[j];
        biasc[g] = bcih[j] + bchh[j];
#pragma unroll
        for (int kc = 0; kc < 2; ++kc) {
            const int off = j * 64 + kc * 32 + q * 8;
            hi8(Whh0 + off, Whi[0][g][kc]);
            hi8(Wih1 + off, Whi[1][g][kc]);
            hi8(Whh1 + off, Whi[2][g][kc]);
        }
        wih0gE[g] = Wih0[j];
        wcihgE[g] = Wcih[j];
    }

    float c0[4], c1[4];
#pragma unroll
    for (int i = 0; i < 4; ++i) { c0[i] = 0.f; c1[i] = 0.f; }

    __syncthreads();

// one fused 2-layer encoder step, ONE barrier; buffer bases are literals
#define ENC_STEP(T, B0P, B0N, B1P, B1N) do {                                          \
        f32x4 xv = *(const f32x4*)(xbF + (T) * Sv + me);                              \
        short8 ah[2];                                                                 \
        _Pragma("unroll")                                                             \
        for (int kc = 0; kc < 2; ++kc)                                                \
            ah[kc] = *(const short8*)(Hhi + (B0P) + roA + kc * 32);                   \
        f32x4 pre0[4];                                                                \
        _Pragma("unroll")                                                             \
        for (int g = 0; g < 4; ++g)                                                   \
            pre0[g] = (f32x4){bias0[g], bias0[g], bias0[g], bias0[g]};                \
        _Pragma("unroll")                                                             \
        for (int g = 0; g < 4; ++g) pre0[g] = MFMA16(ah[0], Whi[0][g][0], pre0[g]);   \
        _Pragma("unroll")                                                             \
        for (int g = 0; g < 4; ++g) pre0[g] = MFMA16(ah[1], Whi[0][g][1], pre0[g]);   \
        _Pragma("unroll")                                                             \
        for (int r = 0; r < 4; ++r) {                                                 \
            const float xw = xv[r];                                                   \
            const float ig = sigm (pre0[0][r] + xw * wih0gE[0]);                      \
            const float fg = sigm (pre0[1][r] + xw * wih0gE[1]);                      \
            const float gt = tanh_(pre0[2][r] + xw * wih0gE[2]);                      \
            const float og = sigm (pre0[3][r] + xw * wih0gE[3]);                      \
            const float c  = fg * c0[r] + ig * gt;                                    \
            c0[r] = c;                                                                \
            Hhi[(B0N) + wiA + r * HSTR] = f2b(og * tanh_(c));                         \
        }                                                                             \
        __syncthreads();   /* the ONLY barrier: h0(new) visible */                    \
        short8 bh[2], dh[2];                                                          \
        _Pragma("unroll")                                                             \
        for (int kc = 0; kc < 2; ++kc) {                                              \
            bh[kc] = *(const short8*)(Hhi + (B0N) + roA + kc * 32);                   \
            dh[kc] = *(const short8*)(Hhi + (B1P) + roA + kc * 32);                   \
        }                                                                             \
        f32x4 pre1[4];                                                                \
        _Pragma("unroll")                                                             \
        for (int g = 0; g < 4; ++g)                                                   \
            pre1[g] = (f32x4){bias1[g], bias1[g], bias1[g], bias1[g]};                \
        _Pragma("unroll")                                                             \
        for (int g = 0; g < 4; ++g) pre1[g] = MFMA16(bh[0], Whi[1][g][0], pre1[g]);   \
        _Pragma("unroll")                                                             \
        for (int g = 0; g < 4; ++g) pre1[g] = MFMA16(bh[1], Whi[1][g][1], pre1[g]);   \
        _Pragma("unroll")                                                             \
        for (int g = 0; g < 4; ++g) pre1[g] = MFMA16(dh[0], Whi[2][g][0], pre1[g]);   \
        _Pragma("unroll")                                                             \
        for (int g = 0; g < 4; ++g) pre1[g] = MFMA16(dh[1], Whi[2][g][1], pre1[g]);   \
        _Pragma("unroll")                                                             \
        for (int r = 0; r < 4; ++r) {                                                 \
            const float ig = sigm (pre1[0][r]);                                       \
            const float fg = sigm (pre1[1][r]);                                       \
            const float gt = tanh_(pre1[2][r]);                                       \
            const float og = sigm (pre1[3][r]);                                       \
            const float c  = fg * c1[r] + ig * gt;                                    \
            c1[r] = c;                                                                \
            Hhi[(B1N) + wiA + r * HSTR] = f2b(og * tanh_(c));                         \
        }                                                                             \
        /* no barrier 2: h1new visibility is provided by next step's barrier,  */     \
        /* which sits before the only B1n reader (next phase 2b)               */     \
    } while (0)

    for (int t = 0; t < Lv; t += 2) {
        ENC_STEP(t,     0 * HBUF, 1 * HBUF, 2 * HBUF, 3 * HBUF);
        ENC_STEP(t + 1, 1 * HBUF, 0 * HBUF, 3 * HBUF, 2 * HBUF);
    }
#undef ENC_STEP

    // ================= decoder =================
#pragma unroll
    for (int g = 0; g < 4; ++g)
#pragma unroll
        for (int kc = 0; kc < 2; ++kc)
            hi8(Wchh + (g * 64 + uu) * 64 + kc * 32 + q * 8, Whi[0][g][kc]);
    if (tid < Mv) ybufF[tid] = xbF[(Lv - 1) * Sv + tid];
    __syncthreads();   // h1(final, buf 2) + ybufF visible

    const float boutF = bout[0];
    float* outp = out + b * HZv * Sv + s0;

#define DEC_STEP(T, B1P, B1N) do {                                                    \
        short8 ah[2];                                                                 \
        _Pragma("unroll")                                                             \
        for (int kc = 0; kc < 2; ++kc)                                                \
            ah[kc] = *(const short8*)(Hhi + (B1P) + roA + kc * 32);                   \
        float yv[4];                                                                  \
        _Pragma("unroll")                                                             \
        for (int r = 0; r < 4; ++r)                                                   \
            yv[r] = ybufF[me + r];                                                    \
        f32x4 prc[4];                                                                 \
        _Pragma("unroll")                                                             \
        for (int g = 0; g < 4; ++g)                                                   \
            prc[g] = (f32x4){biasc[g], biasc[g], biasc[g], biasc[g]};                 \
        _Pragma("unroll")                                                             \
        for (int g = 0; g < 4; ++g) prc[g] = MFMA16(ah[0], Whi[0][g][0], prc[g]);     \
        _Pragma("unroll")                                                             \
        for (int g = 0; g < 4; ++g) prc[g] = MFMA16(ah[1], Whi[0][g][1], prc[g]);     \
        _Pragma("unroll")                                                             \
        for (int r = 0; r < 4; ++r) {                                                 \
            const float xw = yv[r];                                                   \
            const float ig = sigm (prc[0][r] + xw * wcihgE[0]);                       \
            const float fg = sigm (prc[1][r] + xw * wcihgE[1]);                       \
            const float gt = tanh_(prc[2][r] + xw * wcihgE[2]);                       \
            const float og = sigm (prc[3][r] + xw * wcihgE[3]);                       \
            const float c  = fg * c1[r] + ig * gt;                                    \
            c1[r] = c;                                                                \
            Hhi[(B1N) + wiA + r * HSTR] = f2b(og * tanh_(c));                         \
        }                                                                             \
        __syncthreads();   /* h(new) visible for y projection */                      \
        if (tid < 64) {    /* wave 0: 4 lanes per m, 16 k each, shfl reduce */        \
            const int m  = tid >> 2;                                                  \
            const int pp = tid & 3;                                                   \
            float s = 0.f;                                                            \
            _Pragma("unroll")                                                         \
            for (int k = 0; k < 16; ++k)                                              \
                s += b2f(Hhi[(B1N) + m * HSTR + pp * 16 + k]) * woutF[pp * 16 + k];   \
            s += __shfl_xor(s, 1, 64);                                                \
            s += __shfl_xor(s, 2, 64);                                                \
            if (pp == 0) {                                                            \
                const float y = s + boutF;                                            \
                outp[(T) * Sv + m] = y;                                               \
                ybufF[m] = y;                                                         \
            }                                                                         \
        }                                                                             \
        __syncthreads();   /* ybufF visible for next step */                          \
    } while (0)

    for (int t = 0; t < HZv; t += 2) {
        DEC_STEP(t,     2 * HBUF, 3 * HBUF);
        DEC_STEP(t + 1, 3 * HBUF, 2 * HBUF);
    }
#undef DEC_STEP
}

extern "C" void kernel_launch(void* const* d_in, const int* in_sizes, int n_in,
                              void* d_out, int out_size, void* d_ws, size_t ws_size,
                              hipStream_t stream)
{
    const float* x_seq = (const float*)d_in[0];
    const float* Wih0  = (const float*)d_in[1];
    const float* Whh0  = (const float*)d_in[2];
    const float* bih0  = (const float*)d_in[3];
    const float* bhh0  = (const float*)d_in[4];
    const float* Wih1  = (const float*)d_in[5];
    const float* Whh1  = (const float*)d_in[6];
    const float* bih1  = (const float*)d_in[7];
    const float* bhh1  = (const float*)d_in[8];
    const float* Wcih  = (const float*)d_in[9];
    const float* Wchh  = (const float*)d_in[10];
    const float* bcih  = (const float*)d_in[11];
    const float* bchh  = (const float*)d_in[12];
    const float* Wout  = (const float*)d_in[13];
    const float* bout  = (const float*)d_in[14];
    float* out = (float*)d_out;

    hipLaunchKernelGGL(sitewise_lstm, dim3(Bv * (Sv / Mv)), dim3(256), 0, stream,
                       x_seq, Wih0, Whh0, bih0, bhh0, Wih1, Whh1, bih1, bhh1,
                       Wcih, Wchh, bcih, bchh, Wout, bout, out);
}

// Round 3
// 505.920 us; speedup vs baseline: 2.5379x; 2.5379x over previous
//
#include <hip/hip_runtime.h>

typedef __attribute__((ext_vector_type(8))) short short8;
typedef __attribute__((ext_vector_type(4))) float f32x4;

#define MFMA16(a, b, c) __builtin_amdgcn_mfma_f32_16x16x32_bf16((a), (b), (c), 0, 0, 0)

constexpr int Bv  = 32;    // batch
constexpr int Lv  = 168;   // encoder length
constexpr int Sv  = 512;   // sites
constexpr int HZv = 24;    // horizon
constexpr int Mv  = 64;    // sequences per block (256 blocks, 1 per CU)
constexpr int HSTR = 88;   // h-row stride (shorts)
constexpr int HBUF = Mv * HSTR;   // 5632 shorts per buffer
constexpr int WFR  = 512;         // shorts per MFMA B-fragment (64 lanes x 8)
constexpr int WMAT = 32 * WFR;    // 16384 shorts per 256x64 matrix

__device__ __forceinline__ float b2f(short s) {
    unsigned u = ((unsigned)(unsigned short)s) << 16;
    return __builtin_bit_cast(float, u);
}
__device__ __forceinline__ short f2b(float f) {
    unsigned u = __builtin_bit_cast(unsigned, f);
    unsigned r = (u + 0x7FFFu + ((u >> 16) & 1u)) >> 16;   // RNE
    return (short)(unsigned short)r;
}
// no clamps: exp2(inf)=inf, rcp(inf)=0 give exact saturation, no NaN path
__device__ __forceinline__ float sigm(float x) {
    float e = __builtin_amdgcn_exp2f(-1.44269504088896f * x);
    return __builtin_amdgcn_rcpf(1.0f + e);
}
__device__ __forceinline__ float tanh_(float x) {
    float e = __builtin_amdgcn_exp2f(2.88539008177793f * x); // exp(2x)
    return 1.0f - 2.0f * __builtin_amdgcn_rcpf(e + 1.0f);
}
__device__ __forceinline__ void hi8(const float* __restrict__ p, short8& hi) {
#pragma unroll
    for (int j = 0; j < 8; ++j) hi[j] = f2b(p[j]);
}

// r17: 1024-thread block (16 waves = 4 streams/SIMD), M=64, ONE block/CU
// (forced by 140.5 KB LDS). Weights live in LDS as pre-packed conflict-free
// B-fragments (lane l reads base+16l) and are streamed per step in 8-frag
// windows -> peak VGPR ~100, no spill (r16's 4.4 GB scratch traffic was the
// regression). Math + hazard skeleton byte-identical to r15.
__global__ __launch_bounds__(1024)
void sitewise_lstm(const float* __restrict__ x_seq,
                   const float* __restrict__ Wih0, const float* __restrict__ Whh0,
                   const float* __restrict__ bih0, const float* __restrict__ bhh0,
                   const float* __restrict__ Wih1, const float* __restrict__ Whh1,
                   const float* __restrict__ bih1, const float* __restrict__ bhh1,
                   const float* __restrict__ Wcih, const float* __restrict__ Wchh,
                   const float* __restrict__ bcih, const float* __restrict__ bchh,
                   const float* __restrict__ Wout, const float* __restrict__ bout,
                   float* __restrict__ out)
{
    __shared__ __align__(16) short Wlds[3 * WMAT];   // 96 KB  [Whh0|Wih1|Whh1], slot0 -> Wchh in decoder
    __shared__ __align__(16) short Hhi[4 * HBUF];    // 45 KB  h double-buffers, 2 layers
    __shared__ float woutF[64];
    __shared__ float ybufF[Mv];

    const int tid  = threadIdx.x;
    const int wv   = tid >> 6;    // 0..15
    const int lane = tid & 63;
    const int q    = lane >> 4;
    const int col  = lane & 15;
    const int mh   = wv >> 2;     // m-quarter: m in [16mh, 16mh+16)
    const int U    = wv & 3;      // unit-slice: u in [16U, 16U+16)
    const int bid  = blockIdx.x;
    const int b    = bid >> 3;
    const int s0   = (bid & 7) << 6;
    const int uu   = U * 16 + col;
    const int me   = mh * 16 + q * 4;          // epilogue m base (+ r)

    const int roA  = (mh * 16 + col) * HSTR + q * 8;   // A-frag read (+ kc*32)
    const int wiA  = me * HSTR + uu;                   // h write (+ r*HSTR)
    const int wb0  = (U * 8) * WFR + lane * 8;         // mat0 frag base (+ (kc*4+g)*WFR)
    const int wb1  = WMAT + wb0;
    const int wb2  = 2 * WMAT + wb0;

    // ---- zero H buffers ----
    for (int i = tid; i < 4 * HBUF / 2; i += 1024) ((int*)Hhi)[i] = 0;
    if (tid < 64) woutF[tid] = Wout[tid];

    // ---- pack weights into LDS fragments: frag(mat, U,kc,g), lane l holds
    //      W[g*64+U*16+(l&15)][kc*32+(l>>4)*8 .. +8] as bf16 (RNE) ----
    for (int idx = tid; idx < 96 * 64; idx += 1024) {
        const int fid = idx >> 6;          // 0..95
        const int ln  = idx & 63;
        const int mat = fid >> 5;          // 0..2
        const int fm  = fid & 31;          // U*8 + kc*4 + g
        const int Uw  = fm >> 3;
        const int kc  = (fm >> 2) & 1;
        const int g   = fm & 3;
        const float* Wm = (mat == 0) ? Whh0 : (mat == 1) ? Wih1 : Whh1;
        const int j   = g * 64 + Uw * 16 + (ln & 15);
        const int cc  = kc * 32 + (ln >> 4) * 8;
        short8 hv; hi8(Wm + j * 64 + cc, hv);
        *(short8*)(Wlds + fid * WFR + ln * 8) = hv;
    }

    const float* xbF = x_seq + b * Lv * Sv + s0;

    // ---- per-lane scalars ----
    float bias0[4], bias1[4], wih0gE[4];
#pragma unroll
    for (int g = 0; g < 4; ++g) {
        const int j = g * 64 + uu;
        bias0[g]  = bih0[j] + bhh0[j];
        bias1[g]  = bih1[j] + bhh1[j];
        wih0gE[g] = Wih0[j];
    }

    float c0[4], c1[4];
#pragma unroll
    for (int i = 0; i < 4; ++i) { c0[i] = 0.f; c1[i] = 0.f; }

    __syncthreads();   // Hhi zeroed + Wlds packed visible

// one fused 2-layer encoder step, ONE barrier; buffer bases are literals
#define ENC_STEP(T, B0P, B0N, B1P, B1N) do {                                          \
        f32x4 xv = *(const f32x4*)(xbF + (T) * Sv + me);                              \
        short8 ah0 = *(const short8*)(Hhi + (B0P) + roA);                             \
        short8 ah1 = *(const short8*)(Hhi + (B0P) + roA + 32);                        \
        short8 wf[8];                                                                 \
        _Pragma("unroll")                                                             \
        for (int f = 0; f < 8; ++f) wf[f] = *(const short8*)(Wlds + wb0 + f * WFR);   \
        f32x4 pre0[4];                                                                \
        _Pragma("unroll")                                                             \
        for (int g = 0; g < 4; ++g)                                                   \
            pre0[g] = (f32x4){bias0[g], bias0[g], bias0[g], bias0[g]};                \
        _Pragma("unroll")                                                             \
        for (int g = 0; g < 4; ++g) pre0[g] = MFMA16(ah0, wf[g],     pre0[g]);        \
        _Pragma("unroll")                                                             \
        for (int g = 0; g < 4; ++g) pre0[g] = MFMA16(ah1, wf[4 + g], pre0[g]);        \
        _Pragma("unroll")                                                             \
        for (int r = 0; r < 4; ++r) {                                                 \
            const float xw = xv[r];                                                   \
            const float ig = sigm (pre0[0][r] + xw * wih0gE[0]);                      \
            const float fg = sigm (pre0[1][r] + xw * wih0gE[1]);                      \
            const float gt = tanh_(pre0[2][r] + xw * wih0gE[2]);                      \
            const float og = sigm (pre0[3][r] + xw * wih0gE[3]);                      \
            const float c  = fg * c0[r] + ig * gt;                                    \
            c0[r] = c;                                                                \
            Hhi[(B0N) + wiA + r * HSTR] = f2b(og * tanh_(c));                         \
        }                                                                             \
        __syncthreads();   /* the ONLY barrier: h0(new) visible */                    \
        short8 bh0 = *(const short8*)(Hhi + (B0N) + roA);                             \
        short8 bh1 = *(const short8*)(Hhi + (B0N) + roA + 32);                        \
        short8 dh0 = *(const short8*)(Hhi + (B1P) + roA);                             \
        short8 dh1 = *(const short8*)(Hhi + (B1P) + roA + 32);                        \
        f32x4 pre1[4];                                                                \
        _Pragma("unroll")                                                             \
        for (int g = 0; g < 4; ++g)                                                   \
            pre1[g] = (f32x4){bias1[g], bias1[g], bias1[g], bias1[g]};                \
        _Pragma("unroll")                                                             \
        for (int f = 0; f < 8; ++f) wf[f] = *(const short8*)(Wlds + wb1 + f * WFR);   \
        _Pragma("unroll")                                                             \
        for (int g = 0; g < 4; ++g) pre1[g] = MFMA16(bh0, wf[g],     pre1[g]);        \
        _Pragma("unroll")                                                             \
        for (int g = 0; g < 4; ++g) pre1[g] = MFMA16(bh1, wf[4 + g], pre1[g]);        \
        _Pragma("unroll")                                                             \
        for (int f = 0; f < 8; ++f) wf[f] = *(const short8*)(Wlds + wb2 + f * WFR);   \
        _Pragma("unroll")                                                             \
        for (int g = 0; g < 4; ++g) pre1[g] = MFMA16(dh0, wf[g],     pre1[g]);        \
        _Pragma("unroll")                                                             \
        for (int g = 0; g < 4; ++g) pre1[g] = MFMA16(dh1, wf[4 + g], pre1[g]);        \
        _Pragma("unroll")                                                             \
        for (int r = 0; r < 4; ++r) {                                                 \
            const float ig = sigm (pre1[0][r]);                                       \
            const float fg = sigm (pre1[1][r]);                                       \
            const float gt = tanh_(pre1[2][r]);                                       \
            const float og = sigm (pre1[3][r]);                                       \
            const float c  = fg * c1[r] + ig * gt;                                    \
            c1[r] = c;                                                                \
            Hhi[(B1N) + wiA + r * HSTR] = f2b(og * tanh_(c));                         \
        }                                                                             \
        /* no barrier 2: h1new visibility is provided by next step's barrier,  */     \
        /* which sits before the only B1n reader (next phase 2b)               */     \
    } while (0)

    for (int t = 0; t < Lv; t += 2) {
        ENC_STEP(t,     0 * HBUF, 1 * HBUF, 2 * HBUF, 3 * HBUF);
        ENC_STEP(t + 1, 1 * HBUF, 0 * HBUF, 3 * HBUF, 2 * HBUF);
    }
#undef ENC_STEP

    // ================= decoder =================
    // repack mat0 slot <- Wchh (last mat0 read was final phase1, one barrier back)
    for (int idx = tid; idx < 32 * 64; idx += 1024) {
        const int fid = idx >> 6;          // 0..31
        const int ln  = idx & 63;
        const int Uw  = fid >> 3;
        const int kc  = (fid >> 2) & 1;
        const int g   = fid & 3;
        const int j   = g * 64 + Uw * 16 + (ln & 15);
        const int cc  = kc * 32 + (ln >> 4) * 8;
        short8 hv; hi8(Wchh + j * 64 + cc, hv);
        *(short8*)(Wlds + fid * WFR + ln * 8) = hv;
    }
    float biasc[4], wcihgE[4];
#pragma unroll
    for (int g = 0; g < 4; ++g) {
        const int j = g * 64 + uu;
        biasc[g]  = bcih[j] + bchh[j];
        wcihgE[g] = Wcih[j];
    }
    if (tid < Mv) ybufF[tid] = xbF[(Lv - 1) * Sv + tid];
    __syncthreads();   // h1(final, buf 2) + Wchh pack + ybufF visible

    const float boutF = bout[0];
    float* outp = out + b * HZv * Sv + s0;

#define DEC_STEP(T, B1P, B1N) do {                                                    \
        short8 ah0 = *(const short8*)(Hhi + (B1P) + roA);                             \
        short8 ah1 = *(const short8*)(Hhi + (B1P) + roA + 32);                        \
        short8 wf[8];                                                                 \
        _Pragma("unroll")                                                             \
        for (int f = 0; f < 8; ++f) wf[f] = *(const short8*)(Wlds + wb0 + f * WFR);   \
        float yv[4];                                                                  \
        _Pragma("unroll")                                                             \
        for (int r = 0; r < 4; ++r)                                                   \
            yv[r] = ybufF[me + r];                                                    \
        f32x4 prc[4];                                                                 \
        _Pragma("unroll")                                                             \
        for (int g = 0; g < 4; ++g)                                                   \
            prc[g] = (f32x4){biasc[g], biasc[g], biasc[g], biasc[g]};                 \
        _Pragma("unroll")                                                             \
        for (int g = 0; g < 4; ++g) prc[g] = MFMA16(ah0, wf[g],     prc[g]);          \
        _Pragma("unroll")                                                             \
        for (int g = 0; g < 4; ++g) prc[g] = MFMA16(ah1, wf[4 + g], prc[g]);          \
        _Pragma("unroll")                                                             \
        for (int r = 0; r < 4; ++r) {                                                 \
            const float xw = yv[r];                                                   \
            const float ig = sigm (prc[0][r] + xw * wcihgE[0]);                       \
            const float fg = sigm (prc[1][r] + xw * wcihgE[1]);                       \
            const float gt = tanh_(prc[2][r] + xw * wcihgE[2]);                       \
            const float og = sigm (prc[3][r] + xw * wcihgE[3]);                       \
            const float c  = fg * c1[r] + ig * gt;                                    \
            c1[r] = c;                                                                \
            Hhi[(B1N) + wiA + r * HSTR] = f2b(og * tanh_(c));                         \
        }                                                                             \
        __syncthreads();   /* h(new) visible for y projection */                      \
        {                  /* all 1024 threads: 16 lanes per m, 4 k each */           \
            const int m  = tid >> 4;                                                  \
            const int pp = tid & 15;                                                  \
            float s = 0.f;                                                            \
            _Pragma("unroll")                                                         \
            for (int k = 0; k < 4; ++k)                                               \
                s += b2f(Hhi[(B1N) + m * HSTR + pp * 4 + k]) * woutF[pp * 4 + k];     \
            s += __shfl_xor(s, 1, 64);                                                \
            s += __shfl_xor(s, 2, 64);                                                \
            s += __shfl_xor(s, 4, 64);                                                \
            s += __shfl_xor(s, 8, 64);                                                \
            if (pp == 0) {                                                            \
                const float y = s + boutF;                                            \
                outp[(T) * Sv + m] = y;                                               \
                ybufF[m] = y;                                                         \
            }                                                                         \
        }                                                                             \
        __syncthreads();   /* ybufF visible for next step */                          \
    } while (0)

    for (int t = 0; t < HZv; t += 2) {
        DEC_STEP(t,     2 * HBUF, 3 * HBUF);
        DEC_STEP(t + 1, 3 * HBUF, 2 * HBUF);
    }
#undef DEC_STEP
}

extern "C" void kernel_launch(void* const* d_in, const int* in_sizes, int n_in,
                              void* d_out, int out_size, void* d_ws, size_t ws_size,
                              hipStream_t stream)
{
    const float* x_seq = (const float*)d_in[0];
    const float* Wih0  = (const float*)d_in[1];
    const float* Whh0  = (const float*)d_in[2];
    const float* bih0  = (const float*)d_in[3];
    const float* bhh0  = (const float*)d_in[4];
    const float* Wih1  = (const float*)d_in[5];
    const float* Whh1  = (const float*)d_in[6];
    const float* bih1  = (const float*)d_in[7];
    const float* bhh1  = (const float*)d_in[8];
    const float* Wcih  = (const float*)d_in[9];
    const float* Wchh  = (const float*)d_in[10];
    const float* bcih  = (const float*)d_in[11];
    const float* bchh  = (const float*)d_in[12];
    const float* Wout  = (const float*)d_in[13];
    const float* bout  = (const float*)d_in[14];
    float* out = (float*)d_out;

    hipLaunchKernelGGL(sitewise_lstm, dim3(Bv * (Sv / Mv)), dim3(1024), 0, stream,
                       x_seq, Wih0, Whh0, bih0, bhh0, Wih1, Whh1, bih1, bhh1,
                       Wcih, Wchh, bcih, bchh, Wout, bout, out);
}

// Round 5
// 484.629 us; speedup vs baseline: 2.6494x; 1.0439x over previous
//
#include <hip/hip_runtime.h>

typedef __attribute__((ext_vector_type(8))) short short8;
typedef __attribute__((ext_vector_type(4))) float f32x4;

#define MFMA16(a, b, c) __builtin_amdgcn_mfma_f32_16x16x32_bf16((a), (b), (c), 0, 0, 0)

constexpr int Bv  = 32;    // batch
constexpr int Lv  = 168;   // encoder length
constexpr int Sv  = 512;   // sites
constexpr int HZv = 24;    // horizon
constexpr int Mv  = 64;    // sequences per block (256 blocks, 1 per CU)
constexpr int HSTR = 88;   // h-row stride (shorts)
constexpr int HBUF = Mv * HSTR;   // 5632 shorts per buffer
constexpr int WFR  = 512;         // shorts per MFMA B-fragment (64 lanes x 8)
constexpr int WMAT = 32 * WFR;    // 16384 shorts per 256x64 matrix

// gate prescale factors folded into weights/biases at pack time:
// i,f,o rows: -log2(e)  -> sigm(x) = rcp(1 + exp2(p)),  p = -log2e*x
// g row:     2*log2(e)  -> tanh(x) = 1 - 2*rcp(exp2(p)+1), p = 2log2e*x
__device__ __constant__ float GF[4] = {-1.44269504088896f, -1.44269504088896f,
                                        2.88539008177793f, -1.44269504088896f};

__device__ __forceinline__ float b2f(short s) {
    unsigned u = ((unsigned)(unsigned short)s) << 16;
    return __builtin_bit_cast(float, u);
}
__device__ __forceinline__ short f2b(float f) {
    unsigned u = __builtin_bit_cast(unsigned, f);
    unsigned r = (u + 0x7FFFu + ((u >> 16) & 1u)) >> 16;   // RNE
    return (short)(unsigned short)r;
}
// packed f32->bf16 RNE (1 instr for 2 values); no builtin on gfx950 -> asm
__device__ __forceinline__ unsigned pkbf16(float lo, float hi) {
    unsigned r;
    asm("v_cvt_pk_bf16_f32 %0, %1, %2" : "=v"(r) : "v"(lo), "v"(hi));
    return r;
}
// prescaled activations: input already multiplied by the gate factor
__device__ __forceinline__ float sigmP(float p) {            // p = -log2e*x
    float e = __builtin_amdgcn_exp2f(p);
    return __builtin_amdgcn_rcpf(1.0f + e);
}
__device__ __forceinline__ float tanhP(float p) {            // p = 2log2e*x
    float e = __builtin_amdgcn_exp2f(p);
    return 1.0f - 2.0f * __builtin_amdgcn_rcpf(e + 1.0f);
}
__device__ __forceinline__ float tanh_(float x) {            // unscaled (cell)
    float e = __builtin_amdgcn_exp2f(2.88539008177793f * x);
    return 1.0f - 2.0f * __builtin_amdgcn_rcpf(e + 1.0f);
}
__device__ __forceinline__ void hi8s(const float* __restrict__ p, float s, short8& hi) {
#pragma unroll
    for (int j = 0; j < 8; ++j) hi[j] = f2b(p[j] * s);
}

// r18 (resubmit after infra failure): r17 structure (1024-thr block, 16 waves,
// LDS-resident weight frags, ONE barrier/enc-step) + two VALU-count cuts:
//  (1) gate factors prescaled into weights/biases (saves 4 muls/element)
//  (2) h->bf16 via v_cvt_pk_bf16_f32 + d16_hi stores (saves ~20 VALU/lane-step)
__global__ __launch_bounds__(1024)
void sitewise_lstm(const float* __restrict__ x_seq,
                   const float* __restrict__ Wih0, const float* __restrict__ Whh0,
                   const float* __restrict__ bih0, const float* __restrict__ bhh0,
                   const float* __restrict__ Wih1, const float* __restrict__ Whh1,
                   const float* __restrict__ bih1, const float* __restrict__ bhh1,
                   const float* __restrict__ Wcih, const float* __restrict__ Wchh,
                   const float* __restrict__ bcih, const float* __restrict__ bchh,
                   const float* __restrict__ Wout, const float* __restrict__ bout,
                   float* __restrict__ out)
{
    __shared__ __align__(16) short Wlds[3 * WMAT];   // 96 KB  [Whh0|Wih1|Whh1], slot0 -> Wchh in decoder
    __shared__ __align__(16) short Hhi[4 * HBUF];    // 45 KB  h double-buffers, 2 layers
    __shared__ float woutF[64];
    __shared__ float ybufF[Mv];

    const int tid  = threadIdx.x;
    const int wv   = tid >> 6;    // 0..15
    const int lane = tid & 63;
    const int q    = lane >> 4;
    const int col  = lane & 15;
    const int mh   = wv >> 2;     // m-quarter: m in [16mh, 16mh+16)
    const int U    = wv & 3;      // unit-slice: u in [16U, 16U+16)
    const int bid  = blockIdx.x;
    const int b    = bid >> 3;
    const int s0   = (bid & 7) << 6;
    const int uu   = U * 16 + col;
    const int me   = mh * 16 + q * 4;          // epilogue m base (+ r)

    const int roA  = (mh * 16 + col) * HSTR + q * 8;   // A-frag read (+ kc*32)
    const int wiA  = me * HSTR + uu;                   // h write (+ r*HSTR)
    const int wb0  = (U * 8) * WFR + lane * 8;         // mat0 frag base (+ (kc*4+g)*WFR)
    const int wb1  = WMAT + wb0;
    const int wb2  = 2 * WMAT + wb0;

    // ---- zero H buffers ----
    for (int i = tid; i < 4 * HBUF / 2; i += 1024) ((int*)Hhi)[i] = 0;
    if (tid < 64) woutF[tid] = Wout[tid];

    // ---- pack PRESCALED weights into LDS fragments: frag(mat, U,kc,g),
    //      lane l holds GF[g]*W[g*64+U*16+(l&15)][kc*32+(l>>4)*8 ..+8] bf16 ----
    for (int idx = tid; idx < 96 * 64; idx += 1024) {
        const int fid = idx >> 6;          // 0..95
        const int ln  = idx & 63;
        const int mat = fid >> 5;          // 0..2
        const int fm  = fid & 31;          // U*8 + kc*4 + g
        const int Uw  = fm >> 3;
        const int kc  = (fm >> 2) & 1;
        const int g   = fm & 3;
        const float* Wm = (mat == 0) ? Whh0 : (mat == 1) ? Wih1 : Whh1;
        const int j   = g * 64 + Uw * 16 + (ln & 15);
        const int cc  = kc * 32 + (ln >> 4) * 8;
        short8 hv; hi8s(Wm + j * 64 + cc, GF[g], hv);
        *(short8*)(Wlds + fid * WFR + ln * 8) = hv;
    }

    const float* xbF = x_seq + b * Lv * Sv + s0;

    // ---- per-lane scalars (prescaled) ----
    float bias0[4], bias1[4], wih0gE[4];
#pragma unroll
    for (int g = 0; g < 4; ++g) {
        const int j = g * 64 + uu;
        bias0[g]  = (bih0[j] + bhh0[j]) * GF[g];
        bias1[g]  = (bih1[j] + bhh1[j]) * GF[g];
        wih0gE[g] = Wih0[j] * GF[g];
    }

    float c0[4], c1[4];
#pragma unroll
    for (int i = 0; i < 4; ++i) { c0[i] = 0.f; c1[i] = 0.f; }

    __syncthreads();   // Hhi zeroed + Wlds packed visible

// one fused 2-layer encoder step, ONE barrier; buffer bases are literals
#define ENC_STEP(T, B0P, B0N, B1P, B1N) do {                                          \
        f32x4 xv = *(const f32x4*)(xbF + (T) * Sv + me);                              \
        short8 ah0 = *(const short8*)(Hhi + (B0P) + roA);                             \
        short8 ah1 = *(const short8*)(Hhi + (B0P) + roA + 32);                        \
        short8 wf[8];                                                                 \
        _Pragma("unroll")                                                             \
        for (int f = 0; f < 8; ++f) wf[f] = *(const short8*)(Wlds + wb0 + f * WFR);   \
        f32x4 pre0[4];                                                                \
        _Pragma("unroll")                                                             \
        for (int g = 0; g < 4; ++g)                                                   \
            pre0[g] = (f32x4){bias0[g], bias0[g], bias0[g], bias0[g]};                \
        _Pragma("unroll")                                                             \
        for (int g = 0; g < 4; ++g) pre0[g] = MFMA16(ah0, wf[g],     pre0[g]);        \
        _Pragma("unroll")                                                             \
        for (int g = 0; g < 4; ++g) pre0[g] = MFMA16(ah1, wf[4 + g], pre0[g]);        \
        float h0v[4];                                                                 \
        _Pragma("unroll")                                                             \
        for (int r = 0; r < 4; ++r) {                                                 \
            const float xw = xv[r];                                                   \
            const float ig = sigmP(pre0[0][r] + xw * wih0gE[0]);                      \
            const float fg = sigmP(pre0[1][r] + xw * wih0gE[1]);                      \
            const float gt = tanhP(pre0[2][r] + xw * wih0gE[2]);                      \
            const float og = sigmP(pre0[3][r] + xw * wih0gE[3]);                      \
            const float c  = fg * c0[r] + ig * gt;                                    \
            c0[r] = c;                                                                \
            h0v[r] = og * tanh_(c);                                                   \
        }                                                                             \
        {                                                                             \
            const unsigned p01 = pkbf16(h0v[0], h0v[1]);                              \
            const unsigned p23 = pkbf16(h0v[2], h0v[3]);                              \
            Hhi[(B0N) + wiA + 0 * HSTR] = (short)p01;                                 \
            Hhi[(B0N) + wiA + 1 * HSTR] = (short)(p01 >> 16);                         \
            Hhi[(B0N) + wiA + 2 * HSTR] = (short)p23;                                 \
            Hhi[(B0N) + wiA + 3 * HSTR] = (short)(p23 >> 16);                         \
        }                                                                             \
        __syncthreads();   /* the ONLY barrier: h0(new) visible */                    \
        short8 bh0 = *(const short8*)(Hhi + (B0N) + roA);                             \
        short8 bh1 = *(const short8*)(Hhi + (B0N) + roA + 32);                        \
        short8 dh0 = *(const short8*)(Hhi + (B1P) + roA);                             \
        short8 dh1 = *(const short8*)(Hhi + (B1P) + roA + 32);                        \
        f32x4 pre1[4];                                                                \
        _Pragma("unroll")                                                             \
        for (int g = 0; g < 4; ++g)                                                   \
            pre1[g] = (f32x4){bias1[g], bias1[g], bias1[g], bias1[g]};                \
        _Pragma("unroll")                                                             \
        for (int f = 0; f < 8; ++f) wf[f] = *(const short8*)(Wlds + wb1 + f * WFR);   \
        _Pragma("unroll")                                                             \
        for (int g = 0; g < 4; ++g) pre1[g] = MFMA16(bh0, wf[g],     pre1[g]);        \
        _Pragma("unroll")                                                             \
        for (int g = 0; g < 4; ++g) pre1[g] = MFMA16(bh1, wf[4 + g], pre1[g]);        \
        _Pragma("unroll")                                                             \
        for (int f = 0; f < 8; ++f) wf[f] = *(const short8*)(Wlds + wb2 + f * WFR);   \
        _Pragma("unroll")                                                             \
        for (int g = 0; g < 4; ++g) pre1[g] = MFMA16(dh0, wf[g],     pre1[g]);        \
        _Pragma("unroll")                                                             \
        for (int g = 0; g < 4; ++g) pre1[g] = MFMA16(dh1, wf[4 + g], pre1[g]);        \
        float h1v[4];                                                                 \
        _Pragma("unroll")                                                             \
        for (int r = 0; r < 4; ++r) {                                                 \
            const float ig = sigmP(pre1[0][r]);                                       \
            const float fg = sigmP(pre1[1][r]);                                       \
            const float gt = tanhP(pre1[2][r]);                                       \
            const float og = sigmP(pre1[3][r]);                                       \
            const float c  = fg * c1[r] + ig * gt;                                    \
            c1[r] = c;                                                                \
            h1v[r] = og * tanh_(c);                                                   \
        }                                                                             \
        {                                                                             \
            const unsigned p01 = pkbf16(h1v[0], h1v[1]);                              \
            const unsigned p23 = pkbf16(h1v[2], h1v[3]);                              \
            Hhi[(B1N) + wiA + 0 * HSTR] = (short)p01;                                 \
            Hhi[(B1N) + wiA + 1 * HSTR] = (short)(p01 >> 16);                         \
            Hhi[(B1N) + wiA + 2 * HSTR] = (short)p23;                                 \
            Hhi[(B1N) + wiA + 3 * HSTR] = (short)(p23 >> 16);                         \
        }                                                                             \
        /* no barrier 2: h1new visibility is provided by next step's barrier,  */     \
        /* which sits before the only B1n reader (next phase 2b)               */     \
    } while (0)

    for (int t = 0; t < Lv; t += 2) {
        ENC_STEP(t,     0 * HBUF, 1 * HBUF, 2 * HBUF, 3 * HBUF);
        ENC_STEP(t + 1, 1 * HBUF, 0 * HBUF, 3 * HBUF, 2 * HBUF);
    }
#undef ENC_STEP

    // ================= decoder =================
    // repack mat0 slot <- Wchh prescaled (last mat0 read was final phase1)
    for (int idx = tid; idx < 32 * 64; idx += 1024) {
        const int fid = idx >> 6;          // 0..31
        const int ln  = idx & 63;
        const int Uw  = fid >> 3;
        const int kc  = (fid >> 2) & 1;
        const int g   = fid & 3;
        const int j   = g * 64 + Uw * 16 + (ln & 15);
        const int cc  = kc * 32 + (ln >> 4) * 8;
        short8 hv; hi8s(Wchh + j * 64 + cc, GF[g], hv);
        *(short8*)(Wlds + fid * WFR + ln * 8) = hv;
    }
    float biasc[4], wcihgE[4];
#pragma unroll
    for (int g = 0; g < 4; ++g) {
        const int j = g * 64 + uu;
        biasc[g]  = (bcih[j] + bchh[j]) * GF[g];
        wcihgE[g] = Wcih[j] * GF[g];
    }
    if (tid < Mv) ybufF[tid] = xbF[(Lv - 1) * Sv + tid];
    __syncthreads();   // h1(final, buf 2) + Wchh pack + ybufF visible

    const float boutF = bout[0];
    float* outp = out + b * HZv * Sv + s0;

#define DEC_STEP(T, B1P, B1N) do {                                                    \
        short8 ah0 = *(const short8*)(Hhi + (B1P) + roA);                             \
        short8 ah1 = *(const short8*)(Hhi + (B1P) + roA + 32);                        \
        short8 wf[8];                                                                 \
        _Pragma("unroll")                                                             \
        for (int f = 0; f < 8; ++f) wf[f] = *(const short8*)(Wlds + wb0 + f * WFR);   \
        float yv[4];                                                                  \
        _Pragma("unroll")                                                             \
        for (int r = 0; r < 4; ++r)                                                   \
            yv[r] = ybufF[me + r];                                                    \
        f32x4 prc[4];                                                                 \
        _Pragma("unroll")                                                             \
        for (int g = 0; g < 4; ++g)                                                   \
            prc[g] = (f32x4){biasc[g], biasc[g], biasc[g], biasc[g]};                 \
        _Pragma("unroll")                                                             \
        for (int g = 0; g < 4; ++g) prc[g] = MFMA16(ah0, wf[g],     prc[g]);          \
        _Pragma("unroll")                                                             \
        for (int g = 0; g < 4; ++g) prc[g] = MFMA16(ah1, wf[4 + g], prc[g]);          \
        float hdv[4];                                                                 \
        _Pragma("unroll")                                                             \
        for (int r = 0; r < 4; ++r) {                                                 \
            const float xw = yv[r];                                                   \
            const float ig = sigmP(prc[0][r] + xw * wcihgE[0]);                       \
            const float fg = sigmP(prc[1][r] + xw * wcihgE[1]);                       \
            const float gt = tanhP(prc[2][r] + xw * wcihgE[2]);                       \
            const float og = sigmP(prc[3][r] + xw * wcihgE[3]);                       \
            const float c  = fg * c1[r] + ig * gt;                                    \
            c1[r] = c;                                                                \
            hdv[r] = og * tanh_(c);                                                   \
        }                                                                             \
        {                                                                             \
            const unsigned p01 = pkbf16(hdv[0], hdv[1]);                              \
            const unsigned p23 = pkbf16(hdv[2], hdv[3]);                              \
            Hhi[(B1N) + wiA + 0 * HSTR] = (short)p01;                                 \
            Hhi[(B1N) + wiA + 1 * HSTR] = (short)(p01 >> 16);                         \
            Hhi[(B1N) + wiA + 2 * HSTR] = (short)p23;                                 \
            Hhi[(B1N) + wiA + 3 * HSTR] = (short)(p23 >> 16);                         \
        }                                                                             \
        __syncthreads();   /* h(new) visible for y projection */                      \
        {                  /* all 1024 threads: 16 lanes per m, 4 k each */           \
            const int m  = tid >> 4;                                                  \
            const int pp = tid & 15;                                                  \
            float s = 0.f;                                                            \
            _Pragma("unroll")                                                         \
            for (int k = 0; k < 4; ++k)                                               \
                s += b2f(Hhi[(B1N) + m * HSTR + pp * 4 + k]) * woutF[pp * 4 + k];     \
            s += __shfl_xor(s, 1, 64);                                                \
            s += __shfl_xor(s, 2, 64);                                                \
            s += __shfl_xor(s, 4, 64);                                                \
            s += __shfl_xor(s, 8, 64);                                                \
            if (pp == 0) {                                                            \
                const float y = s + boutF;                                            \
                outp[(T) * Sv + m] = y;                                               \
                ybufF[m] = y;                                                         \
            }                                                                         \
        }                                                                             \
        __syncthreads();   /* ybufF visible for next step */                          \
    } while (0)

    for (int t = 0; t < HZv; t += 2) {
        DEC_STEP(t,     2 * HBUF, 3 * HBUF);
        DEC_STEP(t + 1, 3 * HBUF, 2 * HBUF);
    }
#undef DEC_STEP
}

extern "C" void kernel_launch(void* const* d_in, const int* in_sizes, int n_in,
                              void* d_out, int out_size, void* d_ws, size_t ws_size,
                              hipStream_t stream)
{
    const float* x_seq = (const float*)d_in[0];
    const float* Wih0  = (const float*)d_in[1];
    const float* Whh0  = (const float*)d_in[2];
    const float* bih0  = (const float*)d_in[3];
    const float* bhh0  = (const float*)d_in[4];
    const float* Wih1  = (const float*)d_in[5];
    const float* Whh1  = (const float*)d_in[6];
    const float* bih1  = (const float*)d_in[7];
    const float* bhh1  = (const float*)d_in[8];
    const float* Wcih  = (const float*)d_in[9];
    const float* Wchh  = (const float*)d_in[10];
    const float* bcih  = (const float*)d_in[11];
    const float* bchh  = (const float*)d_in[12];
    const float* Wout  = (const float*)d_in[13];
    const float* bout  = (const float*)d_in[14];
    float* out = (float*)d_out;

    hipLaunchKernelGGL(sitewise_lstm, dim3(Bv * (Sv / Mv)), dim3(1024), 0, stream,
                       x_seq, Wih0, Whh0, bih0, bhh0, Wih1, Whh1, bih1, bhh1,
                       Wcih, Wchh, bcih, bchh, Wout, bout, out);
}